// Round 7
// baseline (409.833 us; speedup 1.0000x reference)
//
#include <hip/hip_runtime.h>
#include <hip/hip_cooperative_groups.h>

namespace cg = cooperative_groups;

#define LVAL 256
#define T    32
#define ST   36          // slab row stride (floats): 144 B, 16B-aligned
#define SLAB (T * ST)
#define NB   8
#define NEG  (-1e30f)

// wave-synchronous LDS step fence: drain DS ops + block compiler reordering
#define LDS_FENCE() asm volatile("s_waitcnt lgkmcnt(0)" ::: "memory")

__device__ __forceinline__ size_t sidx(int b, int i, int e) {
    return ((size_t)b << 16) + (i << 8) + e;
}

// VALU cross-lane max via DPP quad_perm (no LDS/swizzle latency)
template<int CTRL>
__device__ __forceinline__ float dpp_max(float v) {
#if __has_builtin(__builtin_amdgcn_mov_dpp)
    int o = __builtin_amdgcn_mov_dpp(__builtin_bit_cast(int, v), CTRL, 0xF, 0xF, true);
    return fmaxf(v, __builtin_bit_cast(float, o));
#else
    return fmaxf(v, __shfl_xor(v, CTRL == 0xB1 ? 1 : 2));
#endif
}

// Phase 1: t[b,i,e] = max_c scores[b,i,e,c] -> f32 s[b][i][e], strict upper only.
__global__ __launch_bounds__(256) void phase1(const float* __restrict__ scores,
                                              float* __restrict__ s) {
    const int i = blockIdx.x, b = blockIdx.y;
    const int sub = threadIdx.x & 15, slot = threadIdx.x >> 4;
    const float* row = scores + ((((size_t)b * LVAL + i) * LVAL) << 6);
    #pragma unroll 4
    for (int m0 = 0; m0 < LVAL; m0 += 16) {
        const int e = m0 + slot;
        if (e > i) {
            float4 v = *((const float4*)(row + ((size_t)e << 6)) + sub);
            float mx = fmaxf(fmaxf(v.x, v.y), fmaxf(v.z, v.w));
            #pragma unroll
            for (int d = 1; d < 16; d <<= 1) mx = fmaxf(mx, __shfl_xor(mx, d));
            if (sub == 0) s[sidx(b, i, e)] = mx;
        }
    }
}

// One wave-synchronous DP step inside a diagonal block (round 0).
template<int LP>
__device__ __forceinline__ void diag_step(int lane, int l,
                                          float (*cur)[ST], float (*curT)[ST],
                                          const float (*tb)[ST]) {
    const int cells = T - l;
    const int P = 1 << LP;
    const int c = lane >> LP, p = lane & (P - 1);
    const bool guard = c < cells;
    const int li = guard ? c : 0;
    const int le = guard ? c + l : 0;
    constexpr int NF = 8 >> LP;
    const float tv = tb[li][le];
    float acc = NEG;
    #pragma unroll
    for (int m = 0; m < NF; ++m) {
        const int k0 = 4 * (p + m * P);
        float4 cu = *(const float4*)&cur[li][k0];
        float4 ct = *(const float4*)&curT[le][k0];
        acc = fmaxf(acc, fmaxf(fmaxf(cu.x + ct.x, cu.y + ct.y),
                               fmaxf(cu.z + ct.z, cu.w + ct.w)));
    }
    acc = dpp_max<0xB1>(acc);
    if (LP >= 2) acc = dpp_max<0x4E>(acc);
    const float v = acc + tv;
    if (guard && p == 0) cur[li][le] = v;
    if (guard && p == 1) curT[le][li] = v;
}

// One wave-synchronous edge step of round D. TRIM=1: first half with ad>=16 —
// left split only k in [16,32), right split only k in [0,16) (rest provably NEG).
template<int LP, int TRIM>
__device__ __forceinline__ void edge_step(int lane, int l, int D,
                                          const float (*Ae)[ST], const float (*BeT)[ST],
                                          float (*cur)[ST], float (*curT)[ST],
                                          const float (*tb)[ST], const float (*pre)[ST]) {
    const int delta = l - (T - 1);
    const int ad = delta < 0 ? -delta : delta;
    const int cells = T - ad;
    const int P = 1 << LP;
    const int c = lane >> LP, p = lane & (P - 1);
    const bool guard = c < cells;
    const int li = guard ? (delta < 0 ? c + ad : c) : 0;
    const int le = guard ? li + delta : 0;
    const float tv = tb[li][le];
    float acc = pre[li][le];                   // middle-K GEMM partial (NEG if none)
    if (TRIM) {                                // ad>=16, first half: 4 chunks each side
        constexpr int NF = 4 >> LP;
        #pragma unroll
        for (int m = 0; m < (NF ? NF : 1); ++m) {
            const int kk = 4 * (p + m * P);
            float4 a  = *(const float4*)&Ae[li][16 + kk];
            float4 ct = *(const float4*)&curT[le][16 + kk];
            float4 cu = *(const float4*)&cur[li][kk];
            float4 bt = *(const float4*)&BeT[le][kk];
            float s0 = fmaxf(fmaxf(a.x + ct.x, a.y + ct.y), fmaxf(a.z + ct.z, a.w + ct.w));
            float s1 = fmaxf(fmaxf(cu.x + bt.x, cu.y + bt.y), fmaxf(cu.z + bt.z, cu.w + bt.w));
            acc = fmaxf(acc, fmaxf(s0, s1));
        }
    } else {
        constexpr int NF = 8 >> LP;
        #pragma unroll
        for (int m = 0; m < NF; ++m) {
            const int k0 = 4 * (p + m * P);
            float4 a  = *(const float4*)&Ae[li][k0];
            float4 ct = *(const float4*)&curT[le][k0];
            float4 cu = *(const float4*)&cur[li][k0];
            float4 bt = *(const float4*)&BeT[le][k0];
            float s0 = fmaxf(fmaxf(a.x + ct.x, a.y + ct.y), fmaxf(a.z + ct.z, a.w + ct.w));
            float s1 = fmaxf(fmaxf(cu.x + bt.x, cu.y + bt.y), fmaxf(cu.z + bt.z, cu.w + bt.w));
            acc = fmaxf(acc, fmaxf(s0, s1));
        }
    }
    acc = dpp_max<0xB1>(acc);
    if (LP >= 2) acc = dpp_max<0x4E>(acc);
    const float v = (D == 1 && l == 0) ? tv : acc + tv;   // w==1 cell: value is t
    if (guard && p == 0) cur[li][le] = v;
    if (guard && p == 1) curT[le][li] = v;
}

// Fused DP: round0 + rounds D=1..7 + finalize. 64 WGs x 256, cooperative.
__global__ __launch_bounds__(256)
void dp_coop(float* __restrict__ s, const int* __restrict__ lens,
             float* __restrict__ out) {
    __shared__ __align__(16) float smem[14 * SLAB];      // 64512 B
    float (*Ae)[ST]   = (float(*)[ST])(smem + 0 * SLAB);
    float (*BeT)[ST]  = (float(*)[ST])(smem + 1 * SLAB);
    float (*cur)[ST]  = (float(*)[ST])(smem + 2 * SLAB);
    float (*curT)[ST] = (float(*)[ST])(smem + 3 * SLAB);
    float (*tb)[ST]   = (float(*)[ST])(smem + 4 * SLAB);
    float (*pre)[ST]  = (float(*)[ST])(smem + 5 * SLAB);
    float* ATb = smem + 6 * SLAB;                        // 4 per-wave A^T slabs
    float* BWb = smem + 10 * SLAB;                       // 4 per-wave B slabs

    cg::grid_group grid = cg::this_grid();
    const int tid = threadIdx.x, wid = tid >> 6, lane = tid & 63;
    const int lr = tid >> 5, lc = tid & 31;
    const int grow = lane >> 1, gc = (lane & 1) * 16;
    const int gly = lane >> 3, glx = lane & 7, r0 = 4 * gly, c0 = 4 * glx;
    float (*AT)[ST] = (float(*)[ST])(ATb + wid * SLAB);
    float (*BW)[ST] = (float(*)[ST])(BWb + wid * SLAB);

    // ---------------- round 0: diagonal blocks, wave 0 only ----------------
    {
        const int bi = blockIdx.x & 7, b = blockIdx.x >> 3;
        if (wid == 0) {
            const int row = lane >> 1, ch = (lane & 1) * 16;
            const float4 negv = make_float4(NEG, NEG, NEG, NEG);
            #pragma unroll
            for (int j = 0; j < 4; ++j) {
                float4 v = *(const float4*)&s[sidx(b, bi * T + row, bi * T + ch + 4 * j)];
                *(float4*)&tb[row][ch + 4 * j]   = v;
                *(float4*)&cur[row][ch + 4 * j]  = negv;
                *(float4*)&curT[row][ch + 4 * j] = negv;
            }
            LDS_FENCE();
            if (lane < T - 1) {                // w == 1 diagonal = t (final)
                float v = tb[lane][lane + 1];
                cur[lane][lane + 1] = v;
                curT[lane + 1][lane] = v;
            }
            LDS_FENCE();
            #pragma unroll 1
            for (int l = 2; l < T; ++l) {
                if (T - l <= 16) diag_step<2>(lane, l, cur, curT, tb);
                else             diag_step<1>(lane, l, cur, curT, tb);
                LDS_FENCE();
            }
            #pragma unroll
            for (int j = 0; j < 4; ++j)
                *(float4*)&s[sidx(b, bi * T + row, bi * T + ch + 4 * j)] =
                    *(const float4*)&cur[row][ch + 4 * j];
        }
        __syncthreads();
    }
    grid.sync();

    // ---------------- rounds D = 1..7 ----------------
    for (int D = 1; D < NB; ++D) {
        const int nbi = NB - D;
        if (blockIdx.x < nbi * 8) {
            const int b = blockIdx.x / nbi, bi = blockIdx.x % nbi, be = bi + D;
            const int nw = (D - 1 < 4) ? (D - 1) : 4;

            // GEMM over middle K blocks: wave-private, statically unrolled
            float ag[4][4];
            #pragma unroll
            for (int i = 0; i < 4; ++i)
                #pragma unroll
                for (int j = 0; j < 4; ++j) ag[i][j] = NEG;
            for (int K = bi + 1 + wid; K < be; K += 4) {
                #pragma unroll
                for (int j = 0; j < 4; ++j) {
                    float4 av = *(const float4*)&s[sidx(b, bi * T + grow, K * T + gc + 4 * j)];
                    AT[gc + 4 * j + 0][grow] = av.x;
                    AT[gc + 4 * j + 1][grow] = av.y;
                    AT[gc + 4 * j + 2][grow] = av.z;
                    AT[gc + 4 * j + 3][grow] = av.w;
                    float4 bv = *(const float4*)&s[sidx(b, K * T + grow, be * T + gc + 4 * j)];
                    *(float4*)&BW[grow][gc + 4 * j] = bv;
                }
                LDS_FENCE();                           // wave-private slabs
                #pragma unroll 4
                for (int k = 0; k < T; ++k) {
                    float4 a4 = *(const float4*)&AT[k][r0];
                    float4 b4 = *(const float4*)&BW[k][c0];
                    const float aa[4] = {a4.x, a4.y, a4.z, a4.w};
                    const float bb[4] = {b4.x, b4.y, b4.z, b4.w};
                    #pragma unroll
                    for (int i = 0; i < 4; ++i)
                        #pragma unroll
                        for (int j = 0; j < 4; ++j)
                            ag[i][j] = fmaxf(ag[i][j], aa[i] + bb[j]);
                }
                LDS_FENCE();
            }
            if (wid < nw) {
                #pragma unroll
                for (int i = 0; i < 4; ++i)
                    *(float4*)&AT[r0 + i][c0] =
                        make_float4(ag[i][0], ag[i][1], ag[i][2], ag[i][3]);
            }
            // edge operands: masked diag blocks + target t + NEG-filled cur/curT
            #pragma unroll
            for (int r = 0; r < 4; ++r) {
                const int row = lr + 8 * r;
                float va = s[sidx(b, bi * T + row, bi * T + lc)];
                Ae[row][lc] = (lc > row) ? va : NEG;
                float vb = s[sidx(b, be * T + row, be * T + lc)];
                BeT[lc][row] = (row < lc) ? vb : NEG;
                tb[row][lc] = s[sidx(b, bi * T + row, be * T + lc)];
                cur[row][lc] = NEG;
                curT[row][lc] = NEG;
            }
            __syncthreads();
            #pragma unroll
            for (int r = 0; r < 4; ++r) {              // combine wave partials
                const int row = lr + 8 * r;
                float v = NEG;
                for (int w2 = 0; w2 < nw; ++w2)
                    v = fmaxf(v, ATb[w2 * SLAB + row * ST + lc]);
                pre[row][lc] = v;
            }
            __syncthreads();

            if (wid == 0) {                            // barrier-free edge pass
                #pragma unroll 1
                for (int l = 0; l < 2 * T - 1; ++l) {
                    const int ad0 = (l < T - 1) ? (T - 1 - l) : (l - (T - 1));
                    if (l < T - 1 && ad0 >= 16)
                        edge_step<2, 1>(lane, l, D, Ae, BeT, cur, curT, tb, pre);
                    else if (ad0 >= 16)
                        edge_step<2, 0>(lane, l, D, Ae, BeT, cur, curT, tb, pre);
                    else
                        edge_step<1, 0>(lane, l, D, Ae, BeT, cur, curT, tb, pre);
                    LDS_FENCE();
                }
            }
            __syncthreads();
            #pragma unroll
            for (int r = 0; r < 4; ++r)
                s[sidx(b, bi * T + lr + 8 * r, be * T + lc)] = cur[lr + 8 * r][lc];

            if (D == NB - 1 && tid == 0) {             // fused finalize (bi==0 -> b)
                int len = lens[b];
                len = len < 1 ? 1 : (len > LVAL - 1 ? LVAL - 1 : len);
                out[b] = (len >= (NB - 1) * T) ? cur[0][len - (NB - 1) * T]
                                               : s[sidx(b, 0, len)];
            }
        }
        grid.sync();
    }
}

extern "C" void kernel_launch(void* const* d_in, const int* in_sizes, int n_in,
                              void* d_out, int out_size, void* d_ws, size_t ws_size,
                              hipStream_t stream) {
    const float* scores = (const float*)d_in[0];
    const int*   lens   = (const int*)d_in[1];
    float*       out    = (float*)d_out;
    float*       s      = (float*)d_ws;               // 8 * 256 * 256 f32 = 2 MB

    phase1<<<dim3(LVAL, 8), 256, 0, stream>>>(scores, s);

    void* args[] = {(void*)&s, (void*)&lens, (void*)&out};
    hipLaunchCooperativeKernel((void*)dp_coop, dim3(64), dim3(256), args, 0, stream);
}